// Round 8
// baseline (408.138 us; speedup 1.0000x reference)
//
#include <hip/hip_runtime.h>
#include <hip/hip_bf16.h>

#define NFEAT 500
#define DIM   64
#define NCLS  40
#define EPS_FA 0.3f
#define NPB   16      // nodes per agg block (4 waves x 4 groups)
#define LDSE  1024    // staged edges per block (mean 256; Poisson never nears 1024)

typedef __attribute__((ext_vector_type(8))) __bf16 bf16x8;
typedef __attribute__((ext_vector_type(4))) float  f32x4;

__device__ __forceinline__ float bf2f(unsigned short u) {
  return __uint_as_float(((unsigned int)u) << 16);
}
__device__ __forceinline__ float fast_tanh(float x) {
  return 1.f - 2.f / (__expf(2.f * x) + 1.f);
}
__device__ __forceinline__ unsigned int packbf(float a, float b) {
  __bf16 x = (__bf16)a, y = (__bf16)b;
  unsigned short ux = *(unsigned short*)&x, uy = *(unsigned short*)&y;
  return (unsigned int)ux | ((unsigned int)uy << 16);
}

// ---------------- CSR build ----------------

__global__ __launch_bounds__(256) void hist_kernel(const int* __restrict__ dst,
                                                   int* __restrict__ deg, int E) {
  int e = blockIdx.x * 256 + threadIdx.x;
  if (e < E) atomicAdd(&deg[dst[e]], 1);
}

__global__ __launch_bounds__(1024) void scan_block_kernel(const int* __restrict__ deg,
                                                          int* __restrict__ offs,
                                                          int* __restrict__ bsums, int n) {
  __shared__ int s[1024];
  int t = threadIdx.x;
  int i = blockIdx.x * 1024 + t;
  int v = (i < n) ? deg[i] : 0;
  s[t] = v;
  __syncthreads();
  for (int off = 1; off < 1024; off <<= 1) {
    int add = (t >= off) ? s[t - off] : 0;
    __syncthreads();
    s[t] += add;
    __syncthreads();
  }
  if (i < n) offs[i] = s[t] - v;
  if (t == 1023) bsums[blockIdx.x] = s[1023];
}

__global__ void scan_sums_kernel(int* __restrict__ bsums, int nb,
                                 int* __restrict__ offs, int n) {
  if (blockIdx.x == 0 && threadIdx.x == 0) {
    int run = 0;
    for (int i = 0; i < nb; ++i) { int v = bsums[i]; bsums[i] = run; run += v; }
    offs[n] = run;
  }
}

__global__ __launch_bounds__(1024) void scan_add_kernel(int* __restrict__ offs,
                                                        const int* __restrict__ bsums, int n) {
  int i = blockIdx.x * 1024 + threadIdx.x;
  if (i < n) offs[i] += bsums[blockIdx.x];
}

// scatter ONE 8B record per edge into CSR order: {src, masked sigmoid(w)}
__global__ __launch_bounds__(256) void scatter_kernel(const int* __restrict__ src,
                                                      const int* __restrict__ dst,
                                                      const float* __restrict__ ewt,
                                                      const int* __restrict__ offs,
                                                      int* __restrict__ cursor,
                                                      int2* __restrict__ edata, int E) {
  int e = blockIdx.x * 256 + threadIdx.x;
  if (e >= E) return;
  int d = dst[e];
  int pos = offs[d] + atomicAdd(&cursor[d], 1);
  float w = ewt[e];
  float sg = (__builtin_fabsf(w) > 0.f) ? (1.f / (1.f + __expf(-w))) : 0.f;
  edata[pos] = make_int2(src[e], __float_as_int(sg));
}

// ---------------- pre-split w into bf16 hi/lo, K padded 500->512 ----------------

__global__ __launch_bounds__(256) void prep_w_kernel(const float* __restrict__ w,
                                                     unsigned short* __restrict__ wh,
                                                     unsigned short* __restrict__ wl) {
  int i = blockIdx.x * 256 + threadIdx.x;     // over 64*512
  int d = i >> 9, k = i & 511;
  float f = (k < NFEAT) ? w[d * NFEAT + k] : 0.f;
  unsigned int u  = __float_as_uint(f);
  unsigned int hi = u & 0xFFFF0000u;
  float        lo = f - __uint_as_float(hi);
  wh[i] = (unsigned short)(u >> 16);
  wl[i] = (unsigned short)(__float_as_uint(lo) >> 16);
}

// ---------------- GEMM1: h = relu(x @ w^T + b), split-bf16 MFMA, fused L1 dots ----
// LDS-FREE: each lane loads its MFMA fragments directly from global.
// A fragment = contiguous 32B of an x row; B fragment from pre-split whg/wlg
// (L2-resident). No barriers -> no vmcnt drains; compiler pipelines freely.

__device__ __forceinline__ void load_a8(const float* __restrict__ xrow, bool mok,
                                        int c0, float4& lo, float4& hi) {
  lo = (float4){0.f, 0.f, 0.f, 0.f};
  hi = (float4){0.f, 0.f, 0.f, 0.f};
  if (mok && c0 < NFEAT) {
    lo = *reinterpret_cast<const float4*>(xrow + c0);       // c0 multiple of 8; 496+4=500 exact
    if (c0 + 8 <= NFEAT)
      hi = *reinterpret_cast<const float4*>(xrow + c0 + 4);
  }
}

__device__ __forceinline__ void split8(float4 lo, float4 hi, bf16x8& ah, bf16x8& al) {
  float f0 = lo.x, f1 = lo.y, f2 = lo.z, f3 = lo.w;
  float f4 = hi.x, f5 = hi.y, f6 = hi.z, f7 = hi.w;
  unsigned int uh[4], ul[4];
  {
    unsigned int a, b; float ra, rb;
#define SPLIT_PAIR(i, fa, fb)                                        \
    a = __float_as_uint(fa); b = __float_as_uint(fb);                \
    ra = fa - __uint_as_float(a & 0xFFFF0000u);                      \
    rb = fb - __uint_as_float(b & 0xFFFF0000u);                      \
    uh[i] = (a >> 16) | (b & 0xFFFF0000u);                           \
    ul[i] = (__float_as_uint(ra) >> 16) | (__float_as_uint(rb) & 0xFFFF0000u);
    SPLIT_PAIR(0, f0, f1)
    SPLIT_PAIR(1, f2, f3)
    SPLIT_PAIR(2, f4, f5)
    SPLIT_PAIR(3, f6, f7)
#undef SPLIT_PAIR
  }
  ah = __builtin_bit_cast(bf16x8, make_uint4(uh[0], uh[1], uh[2], uh[3]));
  al = __builtin_bit_cast(bf16x8, make_uint4(ul[0], ul[1], ul[2], ul[3]));
}

__global__ __launch_bounds__(256) void gemm1_kernel(const float* __restrict__ x,
                                                    const unsigned short* __restrict__ whg,
                                                    const unsigned short* __restrict__ wlg,
                                                    const float* __restrict__ bias,
                                                    const float* __restrict__ al,
                                                    const float* __restrict__ ar,
                                                    unsigned short* __restrict__ hb,
                                                    float* __restrict__ hl,
                                                    float* __restrict__ hr, int n) {
  const int tid  = threadIdx.x;
  const int lane = tid & 63;
  const int wv   = tid >> 6;
  const int m0   = blockIdx.x * 64;
  const int r    = lane & 15;
  const int koff = (lane >> 4) * 8;
  const int rowA = wv * 16 + r;
  const int gm   = m0 + rowA;
  const bool mok = gm < n;
  const float* xrow = x + (size_t)(mok ? gm : 0) * NFEAT;

  f32x4 acc[4];
#pragma unroll
  for (int c = 0; c < 4; ++c) acc[c] = (f32x4){0.f, 0.f, 0.f, 0.f};

  float4 c0l, c0h, c1l, c1h;                       // current iter A (ks=0, ks=1)
  load_a8(xrow, mok, koff,      c0l, c0h);
  load_a8(xrow, mok, 32 + koff, c1l, c1h);

  for (int kb = 0; kb < 512; kb += 64) {
    float4 n0l = {0,0,0,0}, n0h = {0,0,0,0}, n1l = {0,0,0,0}, n1h = {0,0,0,0};
    if (kb + 64 < 512) {                           // prefetch next A (HBM) early
      load_a8(xrow, mok, kb + 64 + koff, n0l, n0h);
      load_a8(xrow, mok, kb + 96 + koff, n1l, n1h);
    }
    bf16x8 ah0, al0, ah1, al1;
    split8(c0l, c0h, ah0, al0);
    split8(c1l, c1h, ah1, al1);
#pragma unroll
    for (int c = 0; c < 4; ++c) {
      const int boff = ((c * 16 + r) << 9) + kb + koff;
      bf16x8 bh0 = *reinterpret_cast<const bf16x8*>(whg + boff);
      bf16x8 bl0 = *reinterpret_cast<const bf16x8*>(wlg + boff);
      bf16x8 bh1 = *reinterpret_cast<const bf16x8*>(whg + boff + 32);
      bf16x8 bl1 = *reinterpret_cast<const bf16x8*>(wlg + boff + 32);
      acc[c] = __builtin_amdgcn_mfma_f32_16x16x32_bf16(ah0, bh0, acc[c], 0, 0, 0);
      acc[c] = __builtin_amdgcn_mfma_f32_16x16x32_bf16(ah0, bl0, acc[c], 0, 0, 0);
      acc[c] = __builtin_amdgcn_mfma_f32_16x16x32_bf16(al0, bh0, acc[c], 0, 0, 0);
      acc[c] = __builtin_amdgcn_mfma_f32_16x16x32_bf16(ah1, bh1, acc[c], 0, 0, 0);
      acc[c] = __builtin_amdgcn_mfma_f32_16x16x32_bf16(ah1, bl1, acc[c], 0, 0, 0);
      acc[c] = __builtin_amdgcn_mfma_f32_16x16x32_bf16(al1, bh1, acc[c], 0, 0, 0);
    }
    c0l = n0l; c0h = n0h; c1l = n1l; c1h = n1h;
  }

  float rowa[4] = {0.f, 0.f, 0.f, 0.f};
  float rowb[4] = {0.f, 0.f, 0.f, 0.f};
#pragma unroll
  for (int c = 0; c < 4; ++c) {
    int col = c * 16 + r;
    float bv = bias[col], alc = al[col], arc = ar[col];
#pragma unroll
    for (int rr = 0; rr < 4; ++rr) {
      int gmo = m0 + wv * 16 + (lane >> 4) * 4 + rr;
      float v = acc[c][rr] + bv;
      v = v > 0.f ? v : 0.f;
      if (gmo < n) {
        __bf16 vb16 = (__bf16)v;
        hb[(size_t)gmo * DIM + col] = *reinterpret_cast<unsigned short*>(&vb16);
      }
      rowa[rr] = fmaf(v, alc, rowa[rr]);
      rowb[rr] = fmaf(v, arc, rowb[rr]);
    }
  }
  // L1 attention dots: reduce over the 16-lane subgroup owning each row
#pragma unroll
  for (int rr = 0; rr < 4; ++rr) {
    float a = rowa[rr], b = rowb[rr];
#pragma unroll
    for (int off = 8; off > 0; off >>= 1) {
      a += __shfl_xor(a, off, 64);
      b += __shfl_xor(b, off, 64);
    }
    if (r == 0) {
      int gmo = m0 + wv * 16 + (lane >> 4) * 4 + rr;
      if (gmo < n) { hl[gmo] = a; hr[gmo] = b; }
    }
  }
}

// ---------------- 4-stream edge loop (one 16-lane group per node) ----------------
// Staged LDS format: {src_byte_off, coef}. Global fallback computes coef inline.

#define EDGE_LOOP(READ_ED)                                                   \
  for (int j = 0; j < mcnt; j += 8) {                                        \
    _Pragma("unroll")                                                        \
    for (int u = 0; u < 8; ++u) {                                            \
      int idx = j + u;                                                       \
      bool valid = idx < cnt;                                                \
      int ci = valid ? s + idx : 0;                                          \
      int2 ed = READ_ED(ci);                                                 \
      int off = valid ? ed.x : 0;                                            \
      float cf = valid ? __int_as_float(ed.y) : 0.f;                         \
      uint2 hv = *reinterpret_cast<const uint2*>((const char*)hb + off + q8);\
      acc.x = fmaf(cf, __uint_as_float(hv.x << 16), acc.x);                  \
      acc.y = fmaf(cf, __uint_as_float(hv.x & 0xffff0000u), acc.y);          \
      acc.z = fmaf(cf, __uint_as_float(hv.y << 16), acc.z);                  \
      acc.w = fmaf(cf, __uint_as_float(hv.y & 0xffff0000u), acc.w);          \
    }                                                                        \
  }
#define RD_LDS(ci) eds[ci]
#define RD_GLB(ci) ({ int2 _e = edata[e0 + (ci)];                            \
      float _c = fast_tanh(hlv[_e.x] + hrd) * __int_as_float(_e.y);          \
      make_int2(_e.x * 128, __float_as_int(_c)); })

// block-cooperative staging with inline coef (dst found by 4-step binary search)
#define STAGE_EDGES(HLV, HRL)                                                \
  for (int i = tid; i < nE && i < LDSE; i += 256) {                          \
    int2 e = edata[e0 + i];                                                  \
    int key = e0 + i;                                                        \
    int nd = 0;                                                              \
    _Pragma("unroll")                                                        \
    for (int st = 8; st >= 1; st >>= 1)                                      \
      if (offs_l[nd + st] <= key) nd += st;                                  \
    float c = fast_tanh(HLV[e.x] + HRL[nd]) * __int_as_float(e.y);           \
    eds[i] = make_int2(e.x * 128, __float_as_int(c));                        \
  }

// ---------------- FAConv layer-1 agg + fused layer-2 dots ----------------

__global__ __launch_bounds__(256) void agg1_kernel(const unsigned short* __restrict__ hb,
                                                   const int2* __restrict__ edata,
                                                   const int* __restrict__ offs,
                                                   const float* __restrict__ hlv,
                                                   const float* __restrict__ hrv,
                                                   const float* __restrict__ al2,
                                                   const float* __restrict__ ar2,
                                                   unsigned short* __restrict__ h1b,
                                                   float* __restrict__ hl2,
                                                   float* __restrict__ hr2, int n) {
  __shared__ int2 eds[LDSE];
  __shared__ int offs_l[NPB + 1];
  __shared__ float hr_l[NPB];
  const int tid  = threadIdx.x;
  const int lane = tid & 63;
  const int wv   = tid >> 6;
  const int g    = lane >> 4;
  const int q    = lane & 15;
  const int q8   = q << 3;
  const int n0   = blockIdx.x * NPB;
  if (tid <= NPB) {
    int nd = n0 + tid;
    offs_l[tid] = offs[nd < n ? nd : n];
  }
  if (tid < NPB) {
    int nd = n0 + tid;
    hr_l[tid] = nd < n ? hrv[nd] : 0.f;
  }
  __syncthreads();
  const int e0 = offs_l[0];
  const int nE = offs_l[NPB] - e0;
  STAGE_EDGES(hlv, hr_l)
  __syncthreads();

  const int node = n0 + wv * 4 + g;
  int s = 0, cnt = 0;
  float hrd = 0.f;
  if (node < n) {
    s = offs_l[wv * 4 + g] - e0;
    cnt = offs_l[wv * 4 + g + 1] - e0 - s;
    hrd = hr_l[wv * 4 + g];
  }
  int mcnt = cnt;
  mcnt = max(mcnt, __shfl_xor(mcnt, 16, 64));
  mcnt = max(mcnt, __shfl_xor(mcnt, 32, 64));

  float4 acc = {0.f, 0.f, 0.f, 0.f};
  if (nE <= LDSE) { EDGE_LOOP(RD_LDS) } else { EDGE_LOOP(RD_GLB) }

  if (node < n) {
    uint2 rv = *reinterpret_cast<const uint2*>((const char*)hb + (size_t)node * 128 + q8);
    float v0 = fmaf(EPS_FA, __uint_as_float(rv.x << 16),         acc.x);
    float v1 = fmaf(EPS_FA, __uint_as_float(rv.x & 0xffff0000u), acc.y);
    float v2 = fmaf(EPS_FA, __uint_as_float(rv.y << 16),         acc.z);
    float v3 = fmaf(EPS_FA, __uint_as_float(rv.y & 0xffff0000u), acc.w);
    uint2 pk = make_uint2(packbf(v0, v1), packbf(v2, v3));
    *reinterpret_cast<uint2*>((char*)h1b + (size_t)node * 128 + q8) = pk;
    const float4 alv = *reinterpret_cast<const float4*>(al2 + q * 4);
    const float4 arv = *reinterpret_cast<const float4*>(ar2 + q * 4);
    float a = v0 * alv.x + v1 * alv.y + v2 * alv.z + v3 * alv.w;
    float b = v0 * arv.x + v1 * arv.y + v2 * arv.z + v3 * arv.w;
#pragma unroll
    for (int off = 8; off > 0; off >>= 1) {
      a += __shfl_xor(a, off, 64);
      b += __shfl_xor(b, off, 64);
    }
    if (q == 0) { hl2[node] = a; hr2[node] = b; }
  }
}

// ---------------- layer-2 agg fused with classifier + log_softmax ----------------

__global__ __launch_bounds__(256) void agg_cls_kernel(const unsigned short* __restrict__ hb,
                                                      const unsigned short* __restrict__ rawb,
                                                      const int2* __restrict__ edata,
                                                      const int* __restrict__ offs,
                                                      const float* __restrict__ hlv,
                                                      const float* __restrict__ hrv,
                                                      const float* __restrict__ t2w,
                                                      const float* __restrict__ t2b,
                                                      float* __restrict__ out, int n) {
  __shared__ int2 eds[LDSE];
  __shared__ int offs_l[NPB + 1];
  __shared__ float hr_l[NPB];
  __shared__ float t2s[DIM * NCLS];     // [k][cls]
  __shared__ float rowbuf[NPB][DIM];
  const int tid  = threadIdx.x;
  const int lane = tid & 63;
  const int wv   = tid >> 6;
  const int g    = lane >> 4;
  const int q    = lane & 15;
  const int q8   = q << 3;
  const int n0   = blockIdx.x * NPB;
  if (tid <= NPB) {
    int nd = n0 + tid;
    offs_l[tid] = offs[nd < n ? nd : n];
  }
  if (tid < NPB) {
    int nd = n0 + tid;
    hr_l[tid] = nd < n ? hrv[nd] : 0.f;
  }
  for (int i = tid; i < DIM * NCLS; i += 256) {
    int k = i / NCLS, cls = i - k * NCLS;
    t2s[i] = t2w[cls * DIM + k];
  }
  __syncthreads();
  const int e0 = offs_l[0];
  const int nE = offs_l[NPB] - e0;
  STAGE_EDGES(hlv, hr_l)
  __syncthreads();

  const int node = n0 + wv * 4 + g;
  int s = 0, cnt = 0;
  float hrd = 0.f;
  if (node < n) {
    s = offs_l[wv * 4 + g] - e0;
    cnt = offs_l[wv * 4 + g + 1] - e0 - s;
    hrd = hr_l[wv * 4 + g];
  }
  int mcnt = cnt;
  mcnt = max(mcnt, __shfl_xor(mcnt, 16, 64));
  mcnt = max(mcnt, __shfl_xor(mcnt, 32, 64));

  float4 acc = {0.f, 0.f, 0.f, 0.f};
  if (nE <= LDSE) { EDGE_LOOP(RD_LDS) } else { EDGE_LOOP(RD_GLB) }

  if (node >= n) return;
  const int nl = wv * 4 + g;
  {
    uint2 rv = *reinterpret_cast<const uint2*>((const char*)rawb + (size_t)node * 128 + q8);
    float4 v;
    v.x = fmaf(EPS_FA, __uint_as_float(rv.x << 16),         acc.x);
    v.y = fmaf(EPS_FA, __uint_as_float(rv.x & 0xffff0000u), acc.y);
    v.z = fmaf(EPS_FA, __uint_as_float(rv.y << 16),         acc.z);
    v.w = fmaf(EPS_FA, __uint_as_float(rv.y & 0xffff0000u), acc.w);
    *reinterpret_cast<float4*>(&rowbuf[nl][q * 4]) = v;   // wave-local: in-order DS pipe
  }
  int c0 = q, c1 = q + 16, c2 = q + 32;
  int c2c = c2 < NCLS ? c2 : 0;
  float lg0 = t2b[c0], lg1 = t2b[c1], lg2 = t2b[c2c];
#pragma unroll
  for (int k = 0; k < DIM; ++k) {
    float rr = rowbuf[nl][k];
    lg0 = fmaf(rr, t2s[k * NCLS + c0], lg0);
    lg1 = fmaf(rr, t2s[k * NCLS + c1], lg1);
    lg2 = fmaf(rr, t2s[k * NCLS + c2c], lg2);
  }
  bool v2ok = c2 < NCLS;
  float mx = fmaxf(fmaxf(lg0, lg1), v2ok ? lg2 : -1e30f);
#pragma unroll
  for (int off = 8; off > 0; off >>= 1) mx = fmaxf(mx, __shfl_xor(mx, off, 64));
  float ssum = __expf(lg0 - mx) + __expf(lg1 - mx) + (v2ok ? __expf(lg2 - mx) : 0.f);
#pragma unroll
  for (int off = 8; off > 0; off >>= 1) ssum += __shfl_xor(ssum, off, 64);
  float lse = mx + __logf(ssum);
  float* op = out + (size_t)node * NCLS;
  op[c0] = lg0 - lse;
  op[c1] = lg1 - lse;
  if (v2ok) op[c2] = lg2 - lse;
}

// ---------------- launch ----------------

extern "C" void kernel_launch(void* const* d_in, const int* in_sizes, int n_in,
                              void* d_out, int out_size, void* d_ws, size_t ws_size,
                              hipStream_t stream) {
  const float* x   = (const float*)d_in[0];
  const int*   ei  = (const int*)d_in[1];
  const float* ewt = (const float*)d_in[2];
  const float* t1w = (const float*)d_in[3];
  const float* t1b = (const float*)d_in[4];
  const float* al1 = (const float*)d_in[5];
  const float* ar1 = (const float*)d_in[6];
  const float* al2 = (const float*)d_in[7];
  const float* ar2 = (const float*)d_in[8];
  const float* t2w = (const float*)d_in[9];
  const float* t2b = (const float*)d_in[10];
  float* out = (float*)d_out;

  const int n = in_sizes[0] / NFEAT;   // 100000
  const int E = in_sizes[2];           // 1600000
  const int* srcp = ei;
  const int* dstp = ei + E;

  char* p = (char*)d_ws;
  auto alloc = [&](size_t bytes) {
    char* q = p;
    p += (bytes + 255) & ~(size_t)255;
    return q;
  };
  unsigned short* h0b = (unsigned short*)alloc((size_t)n * DIM * 2);
  unsigned short* h1b = (unsigned short*)alloc((size_t)n * DIM * 2);
  float* hl    = (float*)alloc((size_t)n * 4);
  float* hr    = (float*)alloc((size_t)n * 4);
  float* hl2   = (float*)alloc((size_t)n * 4);
  float* hr2   = (float*)alloc((size_t)n * 4);
  int*   offs  = (int*)alloc((size_t)(n + 1) * 4);
  int2*  edata = (int2*)alloc((size_t)E * 8);
  unsigned short* whg = (unsigned short*)alloc((size_t)DIM * 512 * 2);
  unsigned short* wlg = (unsigned short*)alloc((size_t)DIM * 512 * 2);
  int*   deg   = (int*)alloc((size_t)n * 4);
  int*   cursor= (int*)alloc((size_t)n * 4);
  int*   bsums = (int*)alloc(4096);

  const int nb = (n + 1023) / 1024;
  const int eb = (E + 255) / 256;

  hipMemsetAsync(deg, 0, (size_t)n * 4, stream);
  hipMemsetAsync(cursor, 0, (size_t)n * 4, stream);

  hist_kernel<<<eb, 256, 0, stream>>>(dstp, deg, E);
  scan_block_kernel<<<nb, 1024, 0, stream>>>(deg, offs, bsums, n);
  scan_sums_kernel<<<1, 64, 0, stream>>>(bsums, nb, offs, n);
  scan_add_kernel<<<nb, 1024, 0, stream>>>(offs, bsums, n);
  scatter_kernel<<<eb, 256, 0, stream>>>(srcp, dstp, ewt, offs, cursor, edata, E);

  prep_w_kernel<<<(DIM * 512) / 256, 256, 0, stream>>>(t1w, whg, wlg);
  gemm1_kernel<<<(n + 63) / 64, 256, 0, stream>>>(x, whg, wlg, t1b, al1, ar1,
                                                  h0b, hl, hr, n);

  const int ab = (n + NPB - 1) / NPB;
  agg1_kernel<<<ab, 256, 0, stream>>>(h0b, edata, offs, hl, hr, al2, ar2, h1b, hl2, hr2, n);
  agg_cls_kernel<<<ab, 256, 0, stream>>>(h1b, h0b, edata, offs, hl2, hr2, t2w, t2b, out, n);
}

// Round 9
// 331.546 us; speedup vs baseline: 1.2310x; 1.2310x over previous
//
#include <hip/hip_runtime.h>
#include <hip/hip_bf16.h>

#define NFEAT 500
#define DIM   64
#define NCLS  40
#define EPS_FA 0.3f
#define NPB   16      // nodes per agg block (4 waves x 4 groups)
#define LDSE  1024    // staged edges per block (mean 256; Poisson never nears 1024)

typedef __attribute__((ext_vector_type(8))) __bf16 bf16x8;
typedef __attribute__((ext_vector_type(4))) float  f32x4;

__device__ __forceinline__ float bf2f(unsigned short u) {
  return __uint_as_float(((unsigned int)u) << 16);
}
__device__ __forceinline__ float fast_tanh(float x) {
  return 1.f - 2.f / (__expf(2.f * x) + 1.f);
}
__device__ __forceinline__ unsigned int packbf(float a, float b) {
  __bf16 x = (__bf16)a, y = (__bf16)b;
  unsigned short ux = *(unsigned short*)&x, uy = *(unsigned short*)&y;
  return (unsigned int)ux | ((unsigned int)uy << 16);
}

// ---------------- CSR build ----------------

__global__ __launch_bounds__(256) void hist_kernel(const int* __restrict__ dst,
                                                   int* __restrict__ deg, int E) {
  int e = blockIdx.x * 256 + threadIdx.x;
  if (e < E) atomicAdd(&deg[dst[e]], 1);
}

__global__ __launch_bounds__(1024) void scan_block_kernel(const int* __restrict__ deg,
                                                          int* __restrict__ offs,
                                                          int* __restrict__ bsums, int n) {
  __shared__ int s[1024];
  int t = threadIdx.x;
  int i = blockIdx.x * 1024 + t;
  int v = (i < n) ? deg[i] : 0;
  s[t] = v;
  __syncthreads();
  for (int off = 1; off < 1024; off <<= 1) {
    int add = (t >= off) ? s[t - off] : 0;
    __syncthreads();
    s[t] += add;
    __syncthreads();
  }
  if (i < n) offs[i] = s[t] - v;
  if (t == 1023) bsums[blockIdx.x] = s[1023];
}

__global__ void scan_sums_kernel(int* __restrict__ bsums, int nb,
                                 int* __restrict__ offs, int n) {
  if (blockIdx.x == 0 && threadIdx.x == 0) {
    int run = 0;
    for (int i = 0; i < nb; ++i) { int v = bsums[i]; bsums[i] = run; run += v; }
    offs[n] = run;
  }
}

__global__ __launch_bounds__(1024) void scan_add_kernel(int* __restrict__ offs,
                                                        const int* __restrict__ bsums, int n) {
  int i = blockIdx.x * 1024 + threadIdx.x;
  if (i < n) offs[i] += bsums[blockIdx.x];
}

// scatter ONE 8B record per edge into CSR order: {src, masked sigmoid(w)}
__global__ __launch_bounds__(256) void scatter_kernel(const int* __restrict__ src,
                                                      const int* __restrict__ dst,
                                                      const float* __restrict__ ewt,
                                                      const int* __restrict__ offs,
                                                      int* __restrict__ cursor,
                                                      int2* __restrict__ edata, int E) {
  int e = blockIdx.x * 256 + threadIdx.x;
  if (e >= E) return;
  int d = dst[e];
  int pos = offs[d] + atomicAdd(&cursor[d], 1);
  float w = ewt[e];
  float sg = (__builtin_fabsf(w) > 0.f) ? (1.f / (1.f + __expf(-w))) : 0.f;
  edata[pos] = make_int2(src[e], __float_as_int(sg));
}

// ---------------- pre-convert w to bf16, K padded 500->512 ----------------

__global__ __launch_bounds__(256) void prep_w_kernel(const float* __restrict__ w,
                                                     unsigned short* __restrict__ wh) {
  int i = blockIdx.x * 256 + threadIdx.x;     // over 64*512
  int d = i >> 9, k = i & 511;
  float f = (k < NFEAT) ? w[d * NFEAT + k] : 0.f;
  __bf16 b = (__bf16)f;
  wh[i] = *reinterpret_cast<unsigned short*>(&b);
}

// ---------------- GEMM1: h = relu(x @ w^T + b), bf16 MFMA, fused L1 dots ----------
// Single-bf16 (storage of h as bf16 already dominates error budget).
// 17 KB LDS, 68-elem padded rows: conflict-free b64 writes / b128 reads.

__global__ __launch_bounds__(256) void gemm1_kernel(const float* __restrict__ x,
                                                    const unsigned short* __restrict__ whg,
                                                    const float* __restrict__ bias,
                                                    const float* __restrict__ al,
                                                    const float* __restrict__ ar,
                                                    unsigned short* __restrict__ hb,
                                                    float* __restrict__ hl,
                                                    float* __restrict__ hr, int n) {
  __shared__ __bf16 Ah[64][68], Bh[64][68];
  const int tid  = threadIdx.x;
  const int lane = tid & 63;
  const int wv   = tid >> 6;
  const int m0   = blockIdx.x * 64;
  const int r    = lane & 15;
  const int koff = (lane >> 4) * 8;
  const int rowA = wv * 16 + r;

  f32x4 acc[4];
#pragma unroll
  for (int c = 0; c < 4; ++c) acc[c] = (f32x4){0.f, 0.f, 0.f, 0.f};

  for (int kb = 0; kb < 512; kb += 64) {
#pragma unroll
    for (int rr = 0; rr < 4; ++rr) {
      int idx = rr * 256 + tid;
      int m   = idx >> 4;             // 0..63
      int k4  = (idx & 15) << 2;      // 0,4,...,60
      int gk  = kb + k4;
      int gm  = m0 + m;
      float4 va = {0.f, 0.f, 0.f, 0.f};
      if (gm < n && gk < NFEAT)
        va = *reinterpret_cast<const float4*>(&x[(size_t)gm * NFEAT + gk]);
      *reinterpret_cast<uint2*>(&Ah[m][k4]) =
          make_uint2(packbf(va.x, va.y), packbf(va.z, va.w));
      *reinterpret_cast<uint2*>(&Bh[m][k4]) =
          *reinterpret_cast<const uint2*>(&whg[m * 512 + gk]);
    }
    __syncthreads();
#pragma unroll
    for (int ks = 0; ks < 2; ++ks) {
      int k0 = ks * 32 + koff;
      bf16x8 a = *reinterpret_cast<const bf16x8*>(&Ah[rowA][k0]);
#pragma unroll
      for (int c = 0; c < 4; ++c) {
        bf16x8 b = *reinterpret_cast<const bf16x8*>(&Bh[c * 16 + r][k0]);
        acc[c] = __builtin_amdgcn_mfma_f32_16x16x32_bf16(a, b, acc[c], 0, 0, 0);
      }
    }
    __syncthreads();
  }

  float rowa[4] = {0.f, 0.f, 0.f, 0.f};
  float rowb[4] = {0.f, 0.f, 0.f, 0.f};
#pragma unroll
  for (int c = 0; c < 4; ++c) {
    int col = c * 16 + r;
    float bv = bias[col], alc = al[col], arc = ar[col];
#pragma unroll
    for (int rr = 0; rr < 4; ++rr) {
      int gmo = m0 + wv * 16 + (lane >> 4) * 4 + rr;
      float v = acc[c][rr] + bv;
      v = v > 0.f ? v : 0.f;
      if (gmo < n) {
        __bf16 vb16 = (__bf16)v;
        hb[(size_t)gmo * DIM + col] = *reinterpret_cast<unsigned short*>(&vb16);
      }
      rowa[rr] = fmaf(v, alc, rowa[rr]);
      rowb[rr] = fmaf(v, arc, rowb[rr]);
    }
  }
  // L1 attention dots: reduce over the 16-lane subgroup owning each row
#pragma unroll
  for (int rr = 0; rr < 4; ++rr) {
    float a = rowa[rr], b = rowb[rr];
#pragma unroll
    for (int off = 8; off > 0; off >>= 1) {
      a += __shfl_xor(a, off, 64);
      b += __shfl_xor(b, off, 64);
    }
    if (r == 0) {
      int gmo = m0 + wv * 16 + (lane >> 4) * 4 + rr;
      if (gmo < n) { hl[gmo] = a; hr[gmo] = b; }
    }
  }
}

// ---------------- 4-stream edge loop (one 16-lane group per node) ----------------
// Staged LDS format: {src_byte_off, coef}. Global fallback computes coef inline.

#define EDGE_LOOP(READ_ED)                                                   \
  for (int j = 0; j < mcnt; j += 8) {                                        \
    _Pragma("unroll")                                                        \
    for (int u = 0; u < 8; ++u) {                                            \
      int idx = j + u;                                                       \
      bool valid = idx < cnt;                                                \
      int ci = valid ? s + idx : 0;                                          \
      int2 ed = READ_ED(ci);                                                 \
      int off = valid ? ed.x : 0;                                            \
      float cf = valid ? __int_as_float(ed.y) : 0.f;                         \
      uint2 hv = *reinterpret_cast<const uint2*>((const char*)hb + off + q8);\
      acc.x = fmaf(cf, __uint_as_float(hv.x << 16), acc.x);                  \
      acc.y = fmaf(cf, __uint_as_float(hv.x & 0xffff0000u), acc.y);          \
      acc.z = fmaf(cf, __uint_as_float(hv.y << 16), acc.z);                  \
      acc.w = fmaf(cf, __uint_as_float(hv.y & 0xffff0000u), acc.w);          \
    }                                                                        \
  }
#define RD_LDS(ci) eds[ci]
#define RD_GLB(ci) ({ int2 _e = edata[e0 + (ci)];                            \
      float _c = fast_tanh(hlv[_e.x] + hrd) * __int_as_float(_e.y);          \
      make_int2(_e.x * 128, __float_as_int(_c)); })

// block-cooperative staging with inline coef (dst found by 4-step binary search)
#define STAGE_EDGES(HLV, HRL)                                                \
  for (int i = tid; i < nE && i < LDSE; i += 256) {                          \
    int2 e = edata[e0 + i];                                                  \
    int key = e0 + i;                                                        \
    int nd = 0;                                                              \
    _Pragma("unroll")                                                        \
    for (int st = 8; st >= 1; st >>= 1)                                      \
      if (offs_l[nd + st] <= key) nd += st;                                  \
    float c = fast_tanh(HLV[e.x] + HRL[nd]) * __int_as_float(e.y);           \
    eds[i] = make_int2(e.x * 128, __float_as_int(c));                        \
  }

// ---------------- FAConv layer-1 agg + fused layer-2 dots ----------------

__global__ __launch_bounds__(256) void agg1_kernel(const unsigned short* __restrict__ hb,
                                                   const int2* __restrict__ edata,
                                                   const int* __restrict__ offs,
                                                   const float* __restrict__ hlv,
                                                   const float* __restrict__ hrv,
                                                   const float* __restrict__ al2,
                                                   const float* __restrict__ ar2,
                                                   unsigned short* __restrict__ h1b,
                                                   float* __restrict__ hl2,
                                                   float* __restrict__ hr2, int n) {
  __shared__ int2 eds[LDSE];
  __shared__ int offs_l[NPB + 1];
  __shared__ float hr_l[NPB];
  const int tid  = threadIdx.x;
  const int lane = tid & 63;
  const int wv   = tid >> 6;
  const int g    = lane >> 4;
  const int q    = lane & 15;
  const int q8   = q << 3;
  const int n0   = blockIdx.x * NPB;
  if (tid <= NPB) {
    int nd = n0 + tid;
    offs_l[tid] = offs[nd < n ? nd : n];
  }
  if (tid < NPB) {
    int nd = n0 + tid;
    hr_l[tid] = nd < n ? hrv[nd] : 0.f;
  }
  __syncthreads();
  const int e0 = offs_l[0];
  const int nE = offs_l[NPB] - e0;
  STAGE_EDGES(hlv, hr_l)
  __syncthreads();

  const int node = n0 + wv * 4 + g;
  int s = 0, cnt = 0;
  float hrd = 0.f;
  if (node < n) {
    s = offs_l[wv * 4 + g] - e0;
    cnt = offs_l[wv * 4 + g + 1] - e0 - s;
    hrd = hr_l[wv * 4 + g];
  }
  int mcnt = cnt;
  mcnt = max(mcnt, __shfl_xor(mcnt, 16, 64));
  mcnt = max(mcnt, __shfl_xor(mcnt, 32, 64));

  float4 acc = {0.f, 0.f, 0.f, 0.f};
  if (nE <= LDSE) { EDGE_LOOP(RD_LDS) } else { EDGE_LOOP(RD_GLB) }

  if (node < n) {
    uint2 rv = *reinterpret_cast<const uint2*>((const char*)hb + (size_t)node * 128 + q8);
    float v0 = fmaf(EPS_FA, __uint_as_float(rv.x << 16),         acc.x);
    float v1 = fmaf(EPS_FA, __uint_as_float(rv.x & 0xffff0000u), acc.y);
    float v2 = fmaf(EPS_FA, __uint_as_float(rv.y << 16),         acc.z);
    float v3 = fmaf(EPS_FA, __uint_as_float(rv.y & 0xffff0000u), acc.w);
    uint2 pk = make_uint2(packbf(v0, v1), packbf(v2, v3));
    *reinterpret_cast<uint2*>((char*)h1b + (size_t)node * 128 + q8) = pk;
    const float4 alv = *reinterpret_cast<const float4*>(al2 + q * 4);
    const float4 arv = *reinterpret_cast<const float4*>(ar2 + q * 4);
    float a = v0 * alv.x + v1 * alv.y + v2 * alv.z + v3 * alv.w;
    float b = v0 * arv.x + v1 * arv.y + v2 * arv.z + v3 * arv.w;
#pragma unroll
    for (int off = 8; off > 0; off >>= 1) {
      a += __shfl_xor(a, off, 64);
      b += __shfl_xor(b, off, 64);
    }
    if (q == 0) { hl2[node] = a; hr2[node] = b; }
  }
}

// ---------------- layer-2 agg fused with classifier + log_softmax ----------------

__global__ __launch_bounds__(256) void agg_cls_kernel(const unsigned short* __restrict__ hb,
                                                      const unsigned short* __restrict__ rawb,
                                                      const int2* __restrict__ edata,
                                                      const int* __restrict__ offs,
                                                      const float* __restrict__ hlv,
                                                      const float* __restrict__ hrv,
                                                      const float* __restrict__ t2w,
                                                      const float* __restrict__ t2b,
                                                      float* __restrict__ out, int n) {
  __shared__ int2 eds[LDSE];
  __shared__ int offs_l[NPB + 1];
  __shared__ float hr_l[NPB];
  __shared__ float t2s[DIM * NCLS];     // [k][cls]
  __shared__ float rowbuf[NPB][DIM];
  const int tid  = threadIdx.x;
  const int lane = tid & 63;
  const int wv   = tid >> 6;
  const int g    = lane >> 4;
  const int q    = lane & 15;
  const int q8   = q << 3;
  const int n0   = blockIdx.x * NPB;
  if (tid <= NPB) {
    int nd = n0 + tid;
    offs_l[tid] = offs[nd < n ? nd : n];
  }
  if (tid < NPB) {
    int nd = n0 + tid;
    hr_l[tid] = nd < n ? hrv[nd] : 0.f;
  }
  for (int i = tid; i < DIM * NCLS; i += 256) {
    int k = i / NCLS, cls = i - k * NCLS;
    t2s[i] = t2w[cls * DIM + k];
  }
  __syncthreads();
  const int e0 = offs_l[0];
  const int nE = offs_l[NPB] - e0;
  STAGE_EDGES(hlv, hr_l)
  __syncthreads();

  const int node = n0 + wv * 4 + g;
  int s = 0, cnt = 0;
  float hrd = 0.f;
  if (node < n) {
    s = offs_l[wv * 4 + g] - e0;
    cnt = offs_l[wv * 4 + g + 1] - e0 - s;
    hrd = hr_l[wv * 4 + g];
  }
  int mcnt = cnt;
  mcnt = max(mcnt, __shfl_xor(mcnt, 16, 64));
  mcnt = max(mcnt, __shfl_xor(mcnt, 32, 64));

  float4 acc = {0.f, 0.f, 0.f, 0.f};
  if (nE <= LDSE) { EDGE_LOOP(RD_LDS) } else { EDGE_LOOP(RD_GLB) }

  if (node >= n) return;
  const int nl = wv * 4 + g;
  {
    uint2 rv = *reinterpret_cast<const uint2*>((const char*)rawb + (size_t)node * 128 + q8);
    float4 v;
    v.x = fmaf(EPS_FA, __uint_as_float(rv.x << 16),         acc.x);
    v.y = fmaf(EPS_FA, __uint_as_float(rv.x & 0xffff0000u), acc.y);
    v.z = fmaf(EPS_FA, __uint_as_float(rv.y << 16),         acc.z);
    v.w = fmaf(EPS_FA, __uint_as_float(rv.y & 0xffff0000u), acc.w);
    *reinterpret_cast<float4*>(&rowbuf[nl][q * 4]) = v;   // wave-local: in-order DS pipe
  }
  int c0 = q, c1 = q + 16, c2 = q + 32;
  int c2c = c2 < NCLS ? c2 : 0;
  float lg0 = t2b[c0], lg1 = t2b[c1], lg2 = t2b[c2c];
#pragma unroll
  for (int k = 0; k < DIM; ++k) {
    float rr = rowbuf[nl][k];
    lg0 = fmaf(rr, t2s[k * NCLS + c0], lg0);
    lg1 = fmaf(rr, t2s[k * NCLS + c1], lg1);
    lg2 = fmaf(rr, t2s[k * NCLS + c2c], lg2);
  }
  bool v2ok = c2 < NCLS;
  float mx = fmaxf(fmaxf(lg0, lg1), v2ok ? lg2 : -1e30f);
#pragma unroll
  for (int off = 8; off > 0; off >>= 1) mx = fmaxf(mx, __shfl_xor(mx, off, 64));
  float ssum = __expf(lg0 - mx) + __expf(lg1 - mx) + (v2ok ? __expf(lg2 - mx) : 0.f);
#pragma unroll
  for (int off = 8; off > 0; off >>= 1) ssum += __shfl_xor(ssum, off, 64);
  float lse = mx + __logf(ssum);
  float* op = out + (size_t)node * NCLS;
  op[c0] = lg0 - lse;
  op[c1] = lg1 - lse;
  if (v2ok) op[c2] = lg2 - lse;
}

// ---------------- launch ----------------

extern "C" void kernel_launch(void* const* d_in, const int* in_sizes, int n_in,
                              void* d_out, int out_size, void* d_ws, size_t ws_size,
                              hipStream_t stream) {
  const float* x   = (const float*)d_in[0];
  const int*   ei  = (const int*)d_in[1];
  const float* ewt = (const float*)d_in[2];
  const float* t1w = (const float*)d_in[3];
  const float* t1b = (const float*)d_in[4];
  const float* al1 = (const float*)d_in[5];
  const float* ar1 = (const float*)d_in[6];
  const float* al2 = (const float*)d_in[7];
  const float* ar2 = (const float*)d_in[8];
  const float* t2w = (const float*)d_in[9];
  const float* t2b = (const float*)d_in[10];
  float* out = (float*)d_out;

  const int n = in_sizes[0] / NFEAT;   // 100000
  const int E = in_sizes[2];           // 1600000
  const int* srcp = ei;
  const int* dstp = ei + E;

  char* p = (char*)d_ws;
  auto alloc = [&](size_t bytes) {
    char* q = p;
    p += (bytes + 255) & ~(size_t)255;
    return q;
  };
  unsigned short* h0b = (unsigned short*)alloc((size_t)n * DIM * 2);
  unsigned short* h1b = (unsigned short*)alloc((size_t)n * DIM * 2);
  float* hl    = (float*)alloc((size_t)n * 4);
  float* hr    = (float*)alloc((size_t)n * 4);
  float* hl2   = (float*)alloc((size_t)n * 4);
  float* hr2   = (float*)alloc((size_t)n * 4);
  int*   offs  = (int*)alloc((size_t)(n + 1) * 4);
  int2*  edata = (int2*)alloc((size_t)E * 8);
  unsigned short* whg = (unsigned short*)alloc((size_t)DIM * 512 * 2);
  int*   deg   = (int*)alloc((size_t)n * 4);
  int*   cursor= (int*)alloc((size_t)n * 4);
  int*   bsums = (int*)alloc(4096);

  const int nb = (n + 1023) / 1024;
  const int eb = (E + 255) / 256;

  hipMemsetAsync(deg, 0, (size_t)n * 4, stream);
  hipMemsetAsync(cursor, 0, (size_t)n * 4, stream);

  hist_kernel<<<eb, 256, 0, stream>>>(dstp, deg, E);
  scan_block_kernel<<<nb, 1024, 0, stream>>>(deg, offs, bsums, n);
  scan_sums_kernel<<<1, 64, 0, stream>>>(bsums, nb, offs, n);
  scan_add_kernel<<<nb, 1024, 0, stream>>>(offs, bsums, n);
  scatter_kernel<<<eb, 256, 0, stream>>>(srcp, dstp, ewt, offs, cursor, edata, E);

  prep_w_kernel<<<(DIM * 512) / 256, 256, 0, stream>>>(t1w, whg);
  gemm1_kernel<<<(n + 63) / 64, 256, 0, stream>>>(x, whg, t1b, al1, ar1,
                                                  h0b, hl, hr, n);

  const int ab = (n + NPB - 1) / NPB;
  agg1_kernel<<<ab, 256, 0, stream>>>(h0b, edata, offs, hl, hr, al2, ar2, h1b, hl2, hr2, n);
  agg_cls_kernel<<<ab, 256, 0, stream>>>(h1b, h0b, edata, offs, hl2, hr2, t2w, t2b, out, n);
}

// Round 10
// 320.536 us; speedup vs baseline: 1.2733x; 1.0343x over previous
//
#include <hip/hip_runtime.h>
#include <hip/hip_bf16.h>

#define NFEAT 500
#define DIM   64
#define NCLS  40
#define EPS_FA 0.3f
#define NPB   32      // nodes per agg block (4 waves x 8 groups)
#define LDSE  1024    // staged edges per block (mean 512; Poisson(512) never nears 1024)

typedef __attribute__((ext_vector_type(8))) __bf16 bf16x8;
typedef __attribute__((ext_vector_type(4))) float  f32x4;

__device__ __forceinline__ float bflo(unsigned int u) {
  return __uint_as_float(u << 16);
}
__device__ __forceinline__ float bfhi(unsigned int u) {
  return __uint_as_float(u & 0xffff0000u);
}
__device__ __forceinline__ float fast_tanh(float x) {
  return 1.f - 2.f / (__expf(2.f * x) + 1.f);
}
__device__ __forceinline__ unsigned int packbf(float a, float b) {
  __bf16 x = (__bf16)a, y = (__bf16)b;
  unsigned short ux = *(unsigned short*)&x, uy = *(unsigned short*)&y;
  return (unsigned int)ux | ((unsigned int)uy << 16);
}

// ---------------- CSR build ----------------

__global__ __launch_bounds__(256) void hist_kernel(const int* __restrict__ dst,
                                                   int* __restrict__ deg, int E) {
  int e = blockIdx.x * 256 + threadIdx.x;
  if (e < E) atomicAdd(&deg[dst[e]], 1);
}

__global__ __launch_bounds__(1024) void scan_block_kernel(const int* __restrict__ deg,
                                                          int* __restrict__ offs,
                                                          int* __restrict__ bsums, int n) {
  __shared__ int s[1024];
  int t = threadIdx.x;
  int i = blockIdx.x * 1024 + t;
  int v = (i < n) ? deg[i] : 0;
  s[t] = v;
  __syncthreads();
  for (int off = 1; off < 1024; off <<= 1) {
    int add = (t >= off) ? s[t - off] : 0;
    __syncthreads();
    s[t] += add;
    __syncthreads();
  }
  if (i < n) offs[i] = s[t] - v;
  if (t == 1023) bsums[blockIdx.x] = s[1023];
}

__global__ void scan_sums_kernel(int* __restrict__ bsums, int nb,
                                 int* __restrict__ offs, int n) {
  if (blockIdx.x == 0 && threadIdx.x == 0) {
    int run = 0;
    for (int i = 0; i < nb; ++i) { int v = bsums[i]; bsums[i] = run; run += v; }
    offs[n] = run;
  }
}

__global__ __launch_bounds__(1024) void scan_add_kernel(int* __restrict__ offs,
                                                        const int* __restrict__ bsums, int n) {
  int i = blockIdx.x * 1024 + threadIdx.x;
  if (i < n) offs[i] += bsums[blockIdx.x];
}

// scatter ONE 8B record per edge into CSR order: {src, masked sigmoid(w)}
__global__ __launch_bounds__(256) void scatter_kernel(const int* __restrict__ src,
                                                      const int* __restrict__ dst,
                                                      const float* __restrict__ ewt,
                                                      const int* __restrict__ offs,
                                                      int* __restrict__ cursor,
                                                      int2* __restrict__ edata, int E) {
  int e = blockIdx.x * 256 + threadIdx.x;
  if (e >= E) return;
  int d = dst[e];
  int pos = offs[d] + atomicAdd(&cursor[d], 1);
  float w = ewt[e];
  float sg = (__builtin_fabsf(w) > 0.f) ? (1.f / (1.f + __expf(-w))) : 0.f;
  edata[pos] = make_int2(src[e], __float_as_int(sg));
}

// ---------------- pre-convert w to bf16, K padded 500->512 ----------------

__global__ __launch_bounds__(256) void prep_w_kernel(const float* __restrict__ w,
                                                     unsigned short* __restrict__ wh) {
  int i = blockIdx.x * 256 + threadIdx.x;     // over 64*512
  int d = i >> 9, k = i & 511;
  float f = (k < NFEAT) ? w[d * NFEAT + k] : 0.f;
  __bf16 b = (__bf16)f;
  wh[i] = *reinterpret_cast<unsigned short*>(&b);
}

// ---------------- GEMM1: h = relu(x @ w^T + b), bf16 MFMA, fused L1 dots ----------

__global__ __launch_bounds__(256) void gemm1_kernel(const float* __restrict__ x,
                                                    const unsigned short* __restrict__ whg,
                                                    const float* __restrict__ bias,
                                                    const float* __restrict__ al,
                                                    const float* __restrict__ ar,
                                                    unsigned short* __restrict__ hb,
                                                    float* __restrict__ hl,
                                                    float* __restrict__ hr, int n) {
  __shared__ __bf16 Ah[64][68], Bh[64][68];
  const int tid  = threadIdx.x;
  const int lane = tid & 63;
  const int wv   = tid >> 6;
  const int m0   = blockIdx.x * 64;
  const int r    = lane & 15;
  const int koff = (lane >> 4) * 8;
  const int rowA = wv * 16 + r;

  f32x4 acc[4];
#pragma unroll
  for (int c = 0; c < 4; ++c) acc[c] = (f32x4){0.f, 0.f, 0.f, 0.f};

  for (int kb = 0; kb < 512; kb += 64) {
#pragma unroll
    for (int rr = 0; rr < 4; ++rr) {
      int idx = rr * 256 + tid;
      int m   = idx >> 4;             // 0..63
      int k4  = (idx & 15) << 2;      // 0,4,...,60
      int gk  = kb + k4;
      int gm  = m0 + m;
      float4 va = {0.f, 0.f, 0.f, 0.f};
      if (gm < n && gk < NFEAT)
        va = *reinterpret_cast<const float4*>(&x[(size_t)gm * NFEAT + gk]);
      *reinterpret_cast<uint2*>(&Ah[m][k4]) =
          make_uint2(packbf(va.x, va.y), packbf(va.z, va.w));
      *reinterpret_cast<uint2*>(&Bh[m][k4]) =
          *reinterpret_cast<const uint2*>(&whg[m * 512 + gk]);
    }
    __syncthreads();
#pragma unroll
    for (int ks = 0; ks < 2; ++ks) {
      int k0 = ks * 32 + koff;
      bf16x8 a = *reinterpret_cast<const bf16x8*>(&Ah[rowA][k0]);
#pragma unroll
      for (int c = 0; c < 4; ++c) {
        bf16x8 b = *reinterpret_cast<const bf16x8*>(&Bh[c * 16 + r][k0]);
        acc[c] = __builtin_amdgcn_mfma_f32_16x16x32_bf16(a, b, acc[c], 0, 0, 0);
      }
    }
    __syncthreads();
  }

  float rowa[4] = {0.f, 0.f, 0.f, 0.f};
  float rowb[4] = {0.f, 0.f, 0.f, 0.f};
#pragma unroll
  for (int c = 0; c < 4; ++c) {
    int col = c * 16 + r;
    float bv = bias[col], alc = al[col], arc = ar[col];
#pragma unroll
    for (int rr = 0; rr < 4; ++rr) {
      int gmo = m0 + wv * 16 + (lane >> 4) * 4 + rr;
      float v = acc[c][rr] + bv;
      v = v > 0.f ? v : 0.f;
      if (gmo < n) {
        __bf16 vb16 = (__bf16)v;
        hb[(size_t)gmo * DIM + col] = *reinterpret_cast<unsigned short*>(&vb16);
      }
      rowa[rr] = fmaf(v, alc, rowa[rr]);
      rowb[rr] = fmaf(v, arc, rowb[rr]);
    }
  }
#pragma unroll
  for (int rr = 0; rr < 4; ++rr) {
    float a = rowa[rr], b = rowb[rr];
#pragma unroll
    for (int off = 8; off > 0; off >>= 1) {
      a += __shfl_xor(a, off, 64);
      b += __shfl_xor(b, off, 64);
    }
    if (r == 0) {
      int gmo = m0 + wv * 16 + (lane >> 4) * 4 + rr;
      if (gmo < n) { hl[gmo] = a; hr[gmo] = b; }
    }
  }
}

// ---------------- 8-stream edge loop (one 8-lane group per node) ----------------
// Lane q owns dims q*8..q*8+7 (16B uint4 per edge). One wave VMEM instruction
// services 8 edges (1KB); unroll 8 => 64 edges in flight per wave.

#define EDGE_LOOP(READ_ED)                                                   \
  for (int j = 0; j < mcnt; j += 8) {                                        \
    _Pragma("unroll")                                                        \
    for (int u = 0; u < 8; ++u) {                                            \
      int idx = j + u;                                                       \
      bool valid = idx < cnt;                                                \
      int ci = valid ? s + idx : 0;                                          \
      int2 ed = READ_ED(ci);                                                 \
      int off = valid ? ed.x : 0;                                            \
      float cf = valid ? __int_as_float(ed.y) : 0.f;                         \
      uint4 hv = *reinterpret_cast<const uint4*>((const char*)hb + off + q16);\
      acc0 = fmaf(cf, bflo(hv.x), acc0); acc1 = fmaf(cf, bfhi(hv.x), acc1);  \
      acc2 = fmaf(cf, bflo(hv.y), acc2); acc3 = fmaf(cf, bfhi(hv.y), acc3);  \
      acc4 = fmaf(cf, bflo(hv.z), acc4); acc5 = fmaf(cf, bfhi(hv.z), acc5);  \
      acc6 = fmaf(cf, bflo(hv.w), acc6); acc7 = fmaf(cf, bfhi(hv.w), acc7);  \
    }                                                                        \
  }
#define RD_LDS(ci) eds[ci]
#define RD_GLB(ci) ({ int2 _e = edata[e0 + (ci)];                            \
      float _c = fast_tanh(hlv[_e.x] + hrd) * __int_as_float(_e.y);          \
      make_int2(_e.x * 128, __float_as_int(_c)); })

// block-cooperative staging with inline coef (dst found by 5-step binary search)
#define STAGE_EDGES(HLV, HRL)                                                \
  for (int i = tid; i < nE && i < LDSE; i += 256) {                          \
    int2 e = edata[e0 + i];                                                  \
    int key = e0 + i;                                                        \
    int nd = 0;                                                              \
    _Pragma("unroll")                                                        \
    for (int st = 16; st >= 1; st >>= 1)                                     \
      if (offs_l[nd + st] <= key) nd += st;                                  \
    float c = fast_tanh(HLV[e.x] + HRL[nd]) * __int_as_float(e.y);           \
    eds[i] = make_int2(e.x * 128, __float_as_int(c));                        \
  }

// common per-kernel group setup
#define AGG_PROLOGUE()                                                       \
  const int tid  = threadIdx.x;                                              \
  const int lane = tid & 63;                                                 \
  const int wv   = tid >> 6;                                                 \
  const int g    = lane >> 3;          /* group 0..7 -> node */              \
  const int q    = lane & 7;           /* dim octet */                       \
  const int q16  = q << 4;                                                   \
  const int n0   = blockIdx.x * NPB;                                         \
  if (tid <= NPB) {                                                          \
    int nd = n0 + tid;                                                       \
    offs_l[tid] = offs[nd < n ? nd : n];                                     \
  }                                                                          \
  if (tid < NPB) {                                                           \
    int nd = n0 + tid;                                                       \
    hr_l[tid] = nd < n ? hrv[nd] : 0.f;                                      \
  }

#define AGG_BODY()                                                           \
  const int e0 = offs_l[0];                                                  \
  const int nE = offs_l[NPB] - e0;                                           \
  STAGE_EDGES(hlv, hr_l)                                                     \
  __syncthreads();                                                           \
  const int node = n0 + wv * 8 + g;                                          \
  int s = 0, cnt = 0;                                                        \
  float hrd = 0.f;                                                           \
  if (node < n) {                                                            \
    s = offs_l[wv * 8 + g] - e0;                                             \
    cnt = offs_l[wv * 8 + g + 1] - e0 - s;                                   \
    hrd = hr_l[wv * 8 + g];                                                  \
  }                                                                          \
  int mcnt = cnt;                                                            \
  mcnt = max(mcnt, __shfl_xor(mcnt, 8, 64));                                 \
  mcnt = max(mcnt, __shfl_xor(mcnt, 16, 64));                                \
  mcnt = max(mcnt, __shfl_xor(mcnt, 32, 64));                                \
  float acc0 = 0.f, acc1 = 0.f, acc2 = 0.f, acc3 = 0.f;                      \
  float acc4 = 0.f, acc5 = 0.f, acc6 = 0.f, acc7 = 0.f;                      \
  if (nE <= LDSE) { EDGE_LOOP(RD_LDS) } else { EDGE_LOOP(RD_GLB) }

// ---------------- FAConv layer-1 agg + fused layer-2 dots ----------------

__global__ __launch_bounds__(256) void agg1_kernel(const unsigned short* __restrict__ hb,
                                                   const int2* __restrict__ edata,
                                                   const int* __restrict__ offs,
                                                   const float* __restrict__ hlv,
                                                   const float* __restrict__ hrv,
                                                   const float* __restrict__ al2,
                                                   const float* __restrict__ ar2,
                                                   unsigned short* __restrict__ h1b,
                                                   float* __restrict__ hl2,
                                                   float* __restrict__ hr2, int n) {
  __shared__ int2 eds[LDSE];
  __shared__ int offs_l[NPB + 1];
  __shared__ float hr_l[NPB];
  AGG_PROLOGUE()
  __syncthreads();
  AGG_BODY()

  if (node < n) {
    uint4 rv = *reinterpret_cast<const uint4*>((const char*)hb + (size_t)node * 128 + q16);
    float v0 = fmaf(EPS_FA, bflo(rv.x), acc0);
    float v1 = fmaf(EPS_FA, bfhi(rv.x), acc1);
    float v2 = fmaf(EPS_FA, bflo(rv.y), acc2);
    float v3 = fmaf(EPS_FA, bfhi(rv.y), acc3);
    float v4 = fmaf(EPS_FA, bflo(rv.z), acc4);
    float v5 = fmaf(EPS_FA, bfhi(rv.z), acc5);
    float v6 = fmaf(EPS_FA, bflo(rv.w), acc6);
    float v7 = fmaf(EPS_FA, bfhi(rv.w), acc7);
    uint4 pk = make_uint4(packbf(v0, v1), packbf(v2, v3), packbf(v4, v5), packbf(v6, v7));
    *reinterpret_cast<uint4*>((char*)h1b + (size_t)node * 128 + q16) = pk;
    // fused layer-2 dots (8-lane group reduce)
    const float4 ala = *reinterpret_cast<const float4*>(al2 + q * 8);
    const float4 alb = *reinterpret_cast<const float4*>(al2 + q * 8 + 4);
    const float4 ara = *reinterpret_cast<const float4*>(ar2 + q * 8);
    const float4 arb = *reinterpret_cast<const float4*>(ar2 + q * 8 + 4);
    float a = v0 * ala.x + v1 * ala.y + v2 * ala.z + v3 * ala.w
            + v4 * alb.x + v5 * alb.y + v6 * alb.z + v7 * alb.w;
    float b = v0 * ara.x + v1 * ara.y + v2 * ara.z + v3 * ara.w
            + v4 * arb.x + v5 * arb.y + v6 * arb.z + v7 * arb.w;
#pragma unroll
    for (int off = 4; off > 0; off >>= 1) {
      a += __shfl_xor(a, off, 64);
      b += __shfl_xor(b, off, 64);
    }
    if (q == 0) { hl2[node] = a; hr2[node] = b; }
  }
}

// ---------------- layer-2 agg fused with classifier + log_softmax ----------------

__global__ __launch_bounds__(256) void agg_cls_kernel(const unsigned short* __restrict__ hb,
                                                      const unsigned short* __restrict__ rawb,
                                                      const int2* __restrict__ edata,
                                                      const int* __restrict__ offs,
                                                      const float* __restrict__ hlv,
                                                      const float* __restrict__ hrv,
                                                      const float* __restrict__ t2w,
                                                      const float* __restrict__ t2b,
                                                      float* __restrict__ out, int n) {
  __shared__ int2 eds[LDSE];
  __shared__ int offs_l[NPB + 1];
  __shared__ float hr_l[NPB];
  __shared__ float t2s[DIM * NCLS];     // [k][cls]
  __shared__ float rowbuf[NPB][DIM];
  AGG_PROLOGUE()
  for (int i = tid; i < DIM * NCLS; i += 256) {
    int k = i / NCLS, cls = i - k * NCLS;
    t2s[i] = t2w[cls * DIM + k];
  }
  __syncthreads();
  AGG_BODY()

  if (node >= n) return;
  const int nl = wv * 8 + g;
  {
    uint4 rv = *reinterpret_cast<const uint4*>((const char*)rawb + (size_t)node * 128 + q16);
    float4 va, vb;
    va.x = fmaf(EPS_FA, bflo(rv.x), acc0);
    va.y = fmaf(EPS_FA, bfhi(rv.x), acc1);
    va.z = fmaf(EPS_FA, bflo(rv.y), acc2);
    va.w = fmaf(EPS_FA, bfhi(rv.y), acc3);
    vb.x = fmaf(EPS_FA, bflo(rv.z), acc4);
    vb.y = fmaf(EPS_FA, bfhi(rv.z), acc5);
    vb.z = fmaf(EPS_FA, bflo(rv.w), acc6);
    vb.w = fmaf(EPS_FA, bfhi(rv.w), acc7);
    *reinterpret_cast<float4*>(&rowbuf[nl][q * 8])     = va;  // wave-local: in-order DS pipe
    *reinterpret_cast<float4*>(&rowbuf[nl][q * 8 + 4]) = vb;
  }
  // classifier: lane q handles classes q+8j, j=0..4 (exactly 40)
  float lg[5];
#pragma unroll
  for (int j = 0; j < 5; ++j) lg[j] = t2b[q + 8 * j];
#pragma unroll
  for (int k = 0; k < DIM; ++k) {
    float rr = rowbuf[nl][k];
#pragma unroll
    for (int j = 0; j < 5; ++j)
      lg[j] = fmaf(rr, t2s[k * NCLS + q + 8 * j], lg[j]);
  }
  float mx = lg[0];
#pragma unroll
  for (int j = 1; j < 5; ++j) mx = fmaxf(mx, lg[j]);
#pragma unroll
  for (int off = 4; off > 0; off >>= 1) mx = fmaxf(mx, __shfl_xor(mx, off, 64));
  float ssum = 0.f;
#pragma unroll
  for (int j = 0; j < 5; ++j) ssum += __expf(lg[j] - mx);
#pragma unroll
  for (int off = 4; off > 0; off >>= 1) ssum += __shfl_xor(ssum, off, 64);
  float lse = mx + __logf(ssum);
  float* op = out + (size_t)node * NCLS;
#pragma unroll
  for (int j = 0; j < 5; ++j) op[q + 8 * j] = lg[j] - lse;
}

// ---------------- launch ----------------

extern "C" void kernel_launch(void* const* d_in, const int* in_sizes, int n_in,
                              void* d_out, int out_size, void* d_ws, size_t ws_size,
                              hipStream_t stream) {
  const float* x   = (const float*)d_in[0];
  const int*   ei  = (const int*)d_in[1];
  const float* ewt = (const float*)d_in[2];
  const float* t1w = (const float*)d_in[3];
  const float* t1b = (const float*)d_in[4];
  const float* al1 = (const float*)d_in[5];
  const float* ar1 = (const float*)d_in[6];
  const float* al2 = (const float*)d_in[7];
  const float* ar2 = (const float*)d_in[8];
  const float* t2w = (const float*)d_in[9];
  const float* t2b = (const float*)d_in[10];
  float* out = (float*)d_out;

  const int n = in_sizes[0] / NFEAT;   // 100000
  const int E = in_sizes[2];           // 1600000
  const int* srcp = ei;
  const int* dstp = ei + E;

  char* p = (char*)d_ws;
  auto alloc = [&](size_t bytes) {
    char* q = p;
    p += (bytes + 255) & ~(size_t)255;
    return q;
  };
  unsigned short* h0b = (unsigned short*)alloc((size_t)n * DIM * 2);
  unsigned short* h1b = (unsigned short*)alloc((size_t)n * DIM * 2);
  float* hl    = (float*)alloc((size_t)n * 4);
  float* hr    = (float*)alloc((size_t)n * 4);
  float* hl2   = (float*)alloc((size_t)n * 4);
  float* hr2   = (float*)alloc((size_t)n * 4);
  int*   offs  = (int*)alloc((size_t)(n + 1) * 4);
  int2*  edata = (int2*)alloc((size_t)E * 8);
  unsigned short* whg = (unsigned short*)alloc((size_t)DIM * 512 * 2);
  int*   deg   = (int*)alloc((size_t)n * 4);      // adjacent to cursor: one memset
  int*   cursor= (int*)alloc((size_t)n * 4);
  int*   bsums = (int*)alloc(4096);

  const int nb = (n + 1023) / 1024;
  const int eb = (E + 255) / 256;

  hipMemsetAsync(deg, 0, (char*)bsums - (char*)deg, stream);  // deg + cursor together

  hist_kernel<<<eb, 256, 0, stream>>>(dstp, deg, E);
  scan_block_kernel<<<nb, 1024, 0, stream>>>(deg, offs, bsums, n);
  scan_sums_kernel<<<1, 64, 0, stream>>>(bsums, nb, offs, n);
  scan_add_kernel<<<nb, 1024, 0, stream>>>(offs, bsums, n);
  scatter_kernel<<<eb, 256, 0, stream>>>(srcp, dstp, ewt, offs, cursor, edata, E);

  prep_w_kernel<<<(DIM * 512) / 256, 256, 0, stream>>>(t1w, whg);
  gemm1_kernel<<<(n + 63) / 64, 256, 0, stream>>>(x, whg, t1b, al1, ar1,
                                                  h0b, hl, hr, n);

  const int ab = (n + NPB - 1) / NPB;
  agg1_kernel<<<ab, 256, 0, stream>>>(h0b, edata, offs, hl, hr, al2, ar2, h1b, hl2, hr2, n);
  agg_cls_kernel<<<ab, 256, 0, stream>>>(h1b, h0b, edata, offs, hl2, hr2, t2w, t2b, out, n);
}